// Round 1
// baseline (222.732 us; speedup 1.0000x reference)
//
#include <hip/hip_runtime.h>

// YOLO loss forward on MI355X.
// input/target: (B=256, C=25, S=64, S=64) fp32, row-major.
// Row for spatial position (b,i,j) = channels strided by S*S floats.
// Memory-bound reduction: 209.7 MB -> 1 float. Target ~33 us at 6.3 TB/s.

#define COORD 5.0f
#define NOOBJ 0.5f

constexpr int B = 256;
constexpr int C = 25;
constexpr int S = 64;
constexpr int SS = S * S;                    // 4096 spatial positions per image
constexpr int CH_STRIDE4 = SS / 4;           // 1024 float4 per channel plane
constexpr int IMG_STRIDE4 = C * CH_STRIDE4;  // 25600 float4 per image
constexpr int N4 = B * SS / 4;               // 262144 float4-groups total

__device__ __forceinline__ float comp(const float4 v, int k) {
    switch (k) {
        case 0: return v.x;
        case 1: return v.y;
        case 2: return v.z;
        default: return v.w;
    }
}

__global__ void zero_out_kernel(float* out) { out[0] = 0.0f; }

__global__ __launch_bounds__(256) void yolo_loss_kernel(
        const float4* __restrict__ in, const float4* __restrict__ tg,
        float* __restrict__ out) {
    const int g = blockIdx.x * blockDim.x + threadIdx.x;
    float acc = 0.0f;
    if (g < N4) {
        const int b = g >> 10;        // / (SS/4)
        const int pp = g & 1023;      // float4 index within channel plane
        const int base = b * IMG_STRIDE4 + pp;

        // Channels 0..4 of both tensors (box + conf)
        float4 p0 = in[base + 0 * CH_STRIDE4];
        float4 p1 = in[base + 1 * CH_STRIDE4];
        float4 p2 = in[base + 2 * CH_STRIDE4];
        float4 p3 = in[base + 3 * CH_STRIDE4];
        float4 p4 = in[base + 4 * CH_STRIDE4];
        float4 t0 = tg[base + 0 * CH_STRIDE4];
        float4 t1 = tg[base + 1 * CH_STRIDE4];
        float4 t2 = tg[base + 2 * CH_STRIDE4];
        float4 t3 = tg[base + 3 * CH_STRIDE4];
        float4 t4 = tg[base + 4 * CH_STRIDE4];

        // objectness mask per sub-position
        float mv[4];
        const float invBlocks = 1.0f / (float)S;

        #pragma unroll
        for (int k = 0; k < 4; ++k) {
            const float px = comp(p0, k), py = comp(p1, k);
            const float pw = comp(p2, k), ph = comp(p3, k);
            const float pc = comp(p4, k);
            const float tx = comp(t0, k), ty = comp(t1, k);
            const float tw = comp(t2, k), th = comp(t3, k);
            const float tc = comp(t4, k);
            const float m = (tc > 0.0f) ? 1.0f : 0.0f;
            mv[k] = m;

            // IoU (forward values only)
            const float c1x = px * invBlocks, c1y = py * invBlocks;
            const float c2x = tx * invBlocks, c2y = ty * invBlocks;
            const float x1a = c1x - pw * 0.5f, x2a = c1x + pw * 0.5f;
            const float y1a = c1y - ph * 0.5f, y2a = c1y + ph * 0.5f;
            const float x1b = c2x - tw * 0.5f, x2b = c2x + tw * 0.5f;
            const float y1b = c2y - th * 0.5f, y2b = c2y + th * 0.5f;
            const float dx = fminf(x2a, x2b) - fmaxf(x1a, x1b);
            const float dy = fminf(y2a, y2b) - fmaxf(y1a, y1b);
            const float inter = dx * dy;
            const float uni = pw * ph + tw * th - inter;
            const bool pos = (dx > 0.0f) && (dy > 0.0f);
            const float iou = pos ? (inter / uni) : 0.0f;

            // coord terms
            const float ex = px - tx, ey = py - ty;
            acc += COORD * m * (ex * ex + ey * ey);
            const float sw = sqrtf(pw) - sqrtf(tw);
            const float sh = sqrtf(ph) - sqrtf(th);
            acc += COORD * m * (sw * sw + sh * sh);
            // confidence terms
            const float ec = pc - iou;
            acc += m * ec * ec;
            acc += NOOBJ * (1.0f - m) * (pc * pc);
        }

        // class terms, channels 5..24
        #pragma unroll
        for (int c = 5; c < 25; ++c) {
            const float4 pv = in[base + c * CH_STRIDE4];
            const float4 tv = tg[base + c * CH_STRIDE4];
            float d;
            d = pv.x - tv.x; acc += mv[0] * d * d;
            d = pv.y - tv.y; acc += mv[1] * d * d;
            d = pv.z - tv.z; acc += mv[2] * d * d;
            d = pv.w - tv.w; acc += mv[3] * d * d;
        }
    }

    // wave64 reduce
    #pragma unroll
    for (int off = 32; off > 0; off >>= 1)
        acc += __shfl_down(acc, off, 64);

    __shared__ float smem[4];
    const int lane = threadIdx.x & 63;
    const int wid = threadIdx.x >> 6;
    if (lane == 0) smem[wid] = acc;
    __syncthreads();
    if (threadIdx.x == 0) {
        const float s = smem[0] + smem[1] + smem[2] + smem[3];
        atomicAdd(out, s);
    }
}

extern "C" void kernel_launch(void* const* d_in, const int* in_sizes, int n_in,
                              void* d_out, int out_size, void* d_ws, size_t ws_size,
                              hipStream_t stream) {
    const float4* in = (const float4*)d_in[0];
    const float4* tg = (const float4*)d_in[1];
    float* out = (float*)d_out;

    // d_out is re-poisoned to 0xAA before every timed launch -> zero it first.
    zero_out_kernel<<<1, 1, 0, stream>>>(out);

    const int threads = 256;
    const int blocks = (N4 + threads - 1) / threads;  // 1024
    yolo_loss_kernel<<<blocks, threads, 0, stream>>>(in, tg, out);
}